// Round 20
// baseline (286.875 us; speedup 1.0000x reference)
//
#include <hip/hip_runtime.h>
#include <math.h>

#define B_ 2
#define S_ 2048
#define D_ 1024
#define H_ 16
#define DH_ 64

typedef _Float16 f16;
typedef _Float16 f16x8 __attribute__((ext_vector_type(8)));
typedef _Float16 f16x4 __attribute__((ext_vector_type(4)));
typedef __fp16 fp16x2 __attribute__((ext_vector_type(2)));
typedef float f32x4 __attribute__((ext_vector_type(4)));

#define MFMA16(a, b, c) __builtin_amdgcn_mfma_f32_16x16x32_f16(a, b, c, 0, 0, 0)
#define LOG2E 1.44269504088896f
#define SHIFT_L2 8.65617024533378f   // 6 * log2(e)

// DPP cross-lane move on VALU pipe (row = 16 lanes on CDNA).
#define DPPF(x, ctrl) \
    __int_as_float(__builtin_amdgcn_mov_dpp(__float_as_int(x), (ctrl), 0xF, 0xF, true))

// k-slot permutation within each 32-column V tile: position p holds
// k = (p>>1) + 16*(p&1)  (pairs (k, k+16) adjacent -> b32 P writes).
__device__ __forceinline__ int permc(int c) {
    return (c & 32) | ((c & 15) << 1) | ((c >> 4) & 1);
}

// ---------------------------------------------------------------------------
// W [k][n] fp32 -> Wht [n][k] f16 (transposed, 3 weights via z).
// ---------------------------------------------------------------------------
__global__ __launch_bounds__(256) void split_w_kernel(
    const float* __restrict__ Wq, const float* __restrict__ Wk,
    const float* __restrict__ Wv, f16* __restrict__ wht)
{
    __shared__ float T[64][69];
    const float* W = (blockIdx.z == 0) ? Wq : (blockIdx.z == 1) ? Wk : Wv;
    f16* ht = wht + (size_t)blockIdx.z * D_ * D_;
    const int t  = threadIdx.x;
    const int k0 = blockIdx.x * 64;
    const int n0 = blockIdx.y * 64;

#pragma unroll
    for (int it = 0; it < 4; ++it) {
        int idx = t + it * 256;
        int row = idx >> 4;
        int c4  = (idx & 15) * 4;
        float4 v = *reinterpret_cast<const float4*>(&W[(size_t)(k0 + row) * D_ + n0 + c4]);
        T[row][c4 + 0] = v.x; T[row][c4 + 1] = v.y;
        T[row][c4 + 2] = v.z; T[row][c4 + 3] = v.w;
    }
    __syncthreads();
#pragma unroll
    for (int it = 0; it < 4; ++it) {
        int idx = t + it * 256;
        int nl = idx >> 4;
        int kc = (idx & 15) * 4;
        f16x4 h4;
#pragma unroll
        for (int j = 0; j < 4; ++j) h4[j] = (f16)T[kc + j][nl];
        *reinterpret_cast<f16x4*>(&ht[(size_t)(n0 + nl) * D_ + k0 + kc]) = h4;
    }
}

// ---------------------------------------------------------------------------
// dist fp32 [4095][64] -> pe f16 [4096][64] (row 4095 dups 4094).
// ---------------------------------------------------------------------------
__global__ __launch_bounds__(256) void pe_convert_kernel(
    const float* __restrict__ dist, f16* __restrict__ pe)
{
    int i = blockIdx.x * 256 + threadIdx.x;
    if (i < 4096 * 16) {
        int src = (i < 4095 * 16) ? i : (i - 16);
        float4 v = reinterpret_cast<const float4*>(dist)[src];
        f16x4 o = {(f16)v.x, (f16)v.y, (f16)v.z, (f16)v.w};
        *reinterpret_cast<f16x4*>(&pe[(size_t)i * 4]) = o;
    }
}

// ---------------------------------------------------------------------------
// MFMA QKV projection, 1-term f16, BK=64. Q pre-scaled by 0.125.
// ---------------------------------------------------------------------------
__global__ __launch_bounds__(256) void mfma_proj_kernel(
    const float* __restrict__ A,
    const f16* __restrict__ wht,
    const float* __restrict__ bq, const float* __restrict__ bk,
    const float* __restrict__ bv,
    f16* __restrict__ qh, f16* __restrict__ kh,
    f16* __restrict__ vt)
{
    __shared__ __align__(16) f16 SM[18432];          // 36 KB
    f16* Ah = SM;                                     // [128][72]
    f16* Wh = SM + 9216;                              // [128][72]

    const int z = blockIdx.z;
    const f16* wh_g = wht + (size_t)z * D_ * D_;
    const float* bias = (z == 0) ? bq : (z == 1) ? bk : bv;
    const float oscale = (z == 0) ? 0.125f : 1.0f;

    const int t    = threadIdx.x;
    const int w    = t >> 6;
    const int lane = t & 63;
    const int lo   = lane & 15;
    const int g    = lane >> 4;
    const int wrow = w >> 1;
    const int wcol = w & 1;
    const int m0   = blockIdx.x * 128;
    const int n0   = blockIdx.y * 128;

    f32x4 acc[4][4];
#pragma unroll
    for (int i = 0; i < 4; ++i)
#pragma unroll
        for (int j = 0; j < 4; ++j) acc[i][j] = (f32x4){0.f, 0.f, 0.f, 0.f};

    for (int k0 = 0; k0 < D_; k0 += 64) {
        __syncthreads();
#pragma unroll
        for (int it = 0; it < 8; ++it) {
            int idx = t + it * 256;
            int row = idx >> 4;
            int c   = idx & 15;
            float4 v = *reinterpret_cast<const float4*>(
                &A[(size_t)(m0 + row) * D_ + k0 + c * 4]);
            f16x4 h4 = {(f16)v.x, (f16)v.y, (f16)v.z, (f16)v.w};
            *reinterpret_cast<f16x4*>(&Ah[row * 72 + c * 4]) = h4;
        }
#pragma unroll
        for (int it = 0; it < 4; ++it) {
            int idx = t + it * 256;
            int row = idx >> 3;
            int c   = idx & 7;
            *reinterpret_cast<f16x8*>(&Wh[row * 72 + c * 8]) =
                *reinterpret_cast<const f16x8*>(&wh_g[(size_t)(n0 + row) * D_ + k0 + c * 8]);
        }
        __syncthreads();

#pragma unroll
        for (int ks = 0; ks < 2; ++ks) {
            f16x8 ah[4], whf[4];
#pragma unroll
            for (int m = 0; m < 4; ++m)
                ah[m] = *reinterpret_cast<const f16x8*>(
                    &Ah[(wrow * 64 + m * 16 + lo) * 72 + ks * 32 + g * 8]);
#pragma unroll
            for (int n = 0; n < 4; ++n)
                whf[n] = *reinterpret_cast<const f16x8*>(
                    &Wh[(wcol * 64 + n * 16 + lo) * 72 + ks * 32 + g * 8]);
#pragma unroll
            for (int m = 0; m < 4; ++m)
#pragma unroll
                for (int n = 0; n < 4; ++n)
                    acc[m][n] = MFMA16(ah[m], whf[n], acc[m][n]);
        }
    }

    float bias_v[4];
#pragma unroll
    for (int n = 0; n < 4; ++n) bias_v[n] = bias[n0 + wcol * 64 + n * 16 + lo];

    __syncthreads();
    f16* vtile = SM + w * 4608;           // per-wave [64][72]
    const int bb = m0 >> 11;

    if (z < 2) {
        f16* hd = (z == 0) ? qh : kh;
#pragma unroll
        for (int n = 0; n < 4; ++n)
#pragma unroll
            for (int m = 0; m < 4; ++m)
#pragma unroll
                for (int r = 0; r < 4; ++r)
                    vtile[(m * 16 + g * 4 + r) * 72 + n * 16 + lo] =
                        (f16)((acc[m][n][r] + bias_v[n]) * oscale);
        int s_base = (m0 & (S_ - 1)) + wrow * 64;
        int col0   = n0 + wcol * 64;
        int hh     = col0 >> 6;
        size_t base = ((size_t)(bb * H_ + hh) * S_ + s_base) * DH_;
#pragma unroll
        for (int it = 0; it < 8; ++it) {
            int idx = lane + it * 64;
            int rl  = idx >> 3;
            int ch  = idx & 7;
            f16x8 vv = *reinterpret_cast<const f16x8*>(&vtile[rl * 72 + ch * 8]);
            *reinterpret_cast<f16x8*>(&hd[base + (size_t)rl * DH_ + ch * 8]) = vv;
        }
    } else {
#pragma unroll
        for (int n = 0; n < 4; ++n)
#pragma unroll
            for (int m = 0; m < 4; ++m)
#pragma unroll
                for (int r = 0; r < 4; ++r) {
                    int c = m * 16 + g * 4 + r;
                    vtile[(n * 16 + lo) * 72 + permc(c)] =
                        (f16)(acc[m][n][r] + bias_v[n]);
                }
        int s_base = (m0 & (S_ - 1)) + wrow * 64;
#pragma unroll
        for (int it = 0; it < 8; ++it) {
            int idx = lane + it * 64;
            int cl  = idx >> 3;
            int mc  = idx & 7;
            f16x8 vv = *reinterpret_cast<const f16x8*>(&vtile[cl * 72 + mc * 8]);
            int col = n0 + wcol * 64 + cl;
            int hh  = col >> 6;
            int dh  = col & 63;
            *reinterpret_cast<f16x8*>(
                &vt[((size_t)(bb * H_ + hh) * DH_ + dh) * S_ + s_base + mc * 8]) = vv;
        }
    }
}

// ---------------------------------------------------------------------------
// MFMA flash attention, v15: KVBLK=64 (2 halves per barrier pair; half body
// identical to R16/R19's proven 32-wide body). Halves barrier crossings
// 128 -> 64 and staging-issue events. PE ring stages 64 rows/iter; rotation
// unchanged per half (each half shifts the band by 32).
// ---------------------------------------------------------------------------
__global__ __launch_bounds__(256) void attn_mfma_kernel(
    const f16* __restrict__ qh, const f16* __restrict__ kh,
    const f16* __restrict__ vt, const f16* __restrict__ pe,
    const float* __restrict__ gm, const float* __restrict__ am,
    float* __restrict__ out)
{
    __shared__ __align__(16) f16 Kh[64 * 72];
    __shared__ __align__(16) f16 Vt[64 * 72];
    __shared__ __align__(16) f16 PE[256 * 72];
    __shared__ __align__(16) f16 Pl[4 * 32 * 40];

    const int t    = threadIdx.x;
    const int w    = t >> 6;
    const int lane = t & 63;
    const int lo   = lane & 15;
    const int g    = lane >> 4;
    const int bh   = blockIdx.y;
    const int b    = bh >> 4;
    const int h    = bh & 15;
    const int l0   = blockIdx.x * 128;
    const int lw   = l0 + w * 32;

    const int krow = t >> 3, kc8 = (t & 7) * 8;   // K & PE staging (32 rows/chunk)
    const int vrow = t >> 2, vc8 = (t & 3) * 8;   // V staging (64 rows, 32-col chunks)

    f16x8 qf[2][2];
#pragma unroll
    for (int sub = 0; sub < 2; ++sub) {
        size_t qbase = ((size_t)bh * S_ + lw + sub * 16 + lo) * DH_ + g * 8;
        qf[sub][0] = *reinterpret_cast<const f16x8*>(qh + qbase);
        qf[sub][1] = *reinterpret_cast<const f16x8*>(qh + qbase + 32);
    }

    // PE prefill: logical rows [l0+2048, l0+2176) (128 rows, clamped)
#pragma unroll
    for (int i = 0; i < 4; ++i) {
        int idx = t + i * 256;
        int row = idx >> 3, c8 = (idx & 7) * 8;
        int logical = l0 + 2048 + row;
        int gl = logical > 4095 ? 4095 : logical;
        *reinterpret_cast<f16x8*>(PE + (size_t)(logical & 255) * 72 + c8) =
            *reinterpret_cast<const f16x8*>(pe + (size_t)gl * DH_ + c8);
    }

    // iter-0 staging: K rows [0,64), V cols [0,64), PE rows [l0+1984, l0+2048)
    f16x8 kreg0, kreg1, vreg0, vreg1, pereg0, pereg1;
    kreg0 = *reinterpret_cast<const f16x8*>(kh + ((size_t)bh * S_ + krow) * DH_ + kc8);
    kreg1 = *reinterpret_cast<const f16x8*>(kh + ((size_t)bh * S_ + krow + 32) * DH_ + kc8);
    vreg0 = *reinterpret_cast<const f16x8*>(vt + ((size_t)bh * DH_ + vrow) * S_ + vc8);
    vreg1 = *reinterpret_cast<const f16x8*>(vt + ((size_t)bh * DH_ + vrow) * S_ + vc8 + 32);
    pereg0 = *reinterpret_cast<const f16x8*>(pe + (size_t)(l0 + 1984 + krow) * DH_ + kc8);
    pereg1 = *reinterpret_cast<const f16x8*>(pe + (size_t)(l0 + 2016 + krow) * DH_ + kc8);

    f32x4 o[2][4];
#pragma unroll
    for (int sub = 0; sub < 2; ++sub)
#pragma unroll
        for (int n = 0; n < 4; ++n) o[sub][n] = (f32x4){0.f, 0.f, 0.f, 0.f};
    float l_part[2][4] = {{0.f, 0.f, 0.f, 0.f}, {0.f, 0.f, 0.f, 0.f}};

    f16* Pw = Pl + w * 32 * 40;

    f16x8 pe0a, pe0b, pe1a, pe1b, pe2a, pe2b, pe3a, pe3b;

    for (int r0 = 0; r0 < S_; r0 += 64) {
        const int Lr = l0 + 1984 - r0;        // staged PE window base
        // ---- write staged regs to LDS ----
        *reinterpret_cast<f16x8*>(Kh + krow * 72 + kc8)        = kreg0;
        *reinterpret_cast<f16x8*>(Kh + (krow + 32) * 72 + kc8) = kreg1;
        *reinterpret_cast<f16x8*>(Vt + vrow * 72 + vc8)        = vreg0;
        *reinterpret_cast<f16x8*>(Vt + vrow * 72 + vc8 + 32)   = vreg1;
        *reinterpret_cast<f16x8*>(PE + (size_t)((Lr + krow) & 255) * 72 + kc8)      = pereg0;
        *reinterpret_cast<f16x8*>(PE + (size_t)((Lr + krow + 32) & 255) * 72 + kc8) = pereg1;
        __syncthreads();

        // ---- issue next-iter staging loads (hide under both halves) ----
        if (r0 + 64 < S_) {
            int r0n = r0 + 64;
            kreg0 = *reinterpret_cast<const f16x8*>(
                kh + ((size_t)bh * S_ + r0n + krow) * DH_ + kc8);
            kreg1 = *reinterpret_cast<const f16x8*>(
                kh + ((size_t)bh * S_ + r0n + krow + 32) * DH_ + kc8);
            vreg0 = *reinterpret_cast<const f16x8*>(
                vt + ((size_t)bh * DH_ + vrow) * S_ + r0n + vc8);
            vreg1 = *reinterpret_cast<const f16x8*>(
                vt + ((size_t)bh * DH_ + vrow) * S_ + r0n + vc8 + 32);
            int Ln = Lr - 64;
            pereg0 = *reinterpret_cast<const f16x8*>(
                pe + (size_t)(Ln + krow) * DH_ + kc8);
            pereg1 = *reinterpret_cast<const f16x8*>(
                pe + (size_t)(Ln + krow + 32) * DH_ + kc8);
        }

#pragma unroll
        for (int hf = 0; hf < 2; ++hf) {
            const int r0h = r0 + hf * 32;
            const int gh  = l0 + 2016 - r0h;

            // ---- gm/am loads for this half (cover under rotation+MFMA) ----
            float gmv[2][2][4];
#pragma unroll
            for (int sub = 0; sub < 2; ++sub)
#pragma unroll
                for (int r = 0; r < 4; ++r) {
                    size_t grow = (size_t)(lw + sub * 16 + g * 4 + r) * S_ + r0h;
                    gmv[sub][0][r] = gm[grow + lo] * LOG2E;
                    gmv[sub][1][r] = gm[grow + 16 + lo] * LOG2E;
                }
            float amL0 = fmaf(am[b * S_ + r0h + lo],      LOG2E, -SHIFT_L2);
            float amL1 = fmaf(am[b * S_ + r0h + 16 + lo], LOG2E, -SHIFT_L2);

            // ---- PE tile rotation (per half, shift 32) ----
            {
                int pr0 = (gh + w * 32 + lo) & 255;
                int pr1 = (gh + w * 32 + 16 + lo) & 255;
                f16x8 n0a = *reinterpret_cast<const f16x8*>(PE + (size_t)pr0 * 72 + g * 8);
                f16x8 n0b = *reinterpret_cast<const f16x8*>(PE + (size_t)pr0 * 72 + 32 + g * 8);
                f16x8 n1a = *reinterpret_cast<const f16x8*>(PE + (size_t)pr1 * 72 + g * 8);
                f16x8 n1b = *reinterpret_cast<const f16x8*>(PE + (size_t)pr1 * 72 + 32 + g * 8);
                if (r0h == 0) {
                    int pr2 = (gh + w * 32 + 32 + lo) & 255;
                    int pr3 = (gh + w * 32 + 48 + lo) & 255;
                    pe2a = *reinterpret_cast<const f16x8*>(PE + (size_t)pr2 * 72 + g * 8);
                    pe2b = *reinterpret_cast<const f16x8*>(PE + (size_t)pr2 * 72 + 32 + g * 8);
                    pe3a = *reinterpret_cast<const f16x8*>(PE + (size_t)pr3 * 72 + g * 8);
                    pe3b = *reinterpret_cast<const f16x8*>(PE + (size_t)pr3 * 72 + 32 + g * 8);
                } else {
                    pe2a = pe0a; pe2b = pe0b;
                    pe3a = pe1a; pe3b = pe1b;
                }
                pe0a = n0a; pe0b = n0b;
                pe1a = n1a; pe1b = n1b;
            }

            // ---- QK^T (K rows offset by hf*32) ----
            f32x4 sc[2][2];
            sc[0][0] = (f32x4){0.f,0.f,0.f,0.f}; sc[0][1] = (f32x4){0.f,0.f,0.f,0.f};
            sc[1][0] = (f32x4){0.f,0.f,0.f,0.f}; sc[1][1] = (f32x4){0.f,0.f,0.f,0.f};
#pragma unroll
            for (int u = 0; u < 2; ++u)
#pragma unroll
                for (int s = 0; s < 2; ++s) {
                    f16x8 kb = *reinterpret_cast<const f16x8*>(
                        Kh + (hf * 32 + u * 16 + lo) * 72 + s * 32 + g * 8);
                    sc[0][u] = MFMA16(qf[0][s], kb, sc[0][u]);
                    sc[1][u] = MFMA16(qf[1][s], kb, sc[1][u]);
                }
            // ---- bias band from rotated register tiles ----
            f32x4 mmA[3], mmB[3];
#pragma unroll
            for (int i = 0; i < 3; ++i) {
                mmA[i] = (f32x4){0.f,0.f,0.f,0.f};
                mmB[i] = (f32x4){0.f,0.f,0.f,0.f};
            }
            mmA[0] = MFMA16(qf[0][0], pe0a, mmA[0]);
            mmA[0] = MFMA16(qf[0][1], pe0b, mmA[0]);
            mmA[1] = MFMA16(qf[0][0], pe1a, mmA[1]);
            mmA[1] = MFMA16(qf[0][1], pe1b, mmA[1]);
            mmB[0] = MFMA16(qf[1][0], pe1a, mmB[0]);
            mmB[0] = MFMA16(qf[1][1], pe1b, mmB[0]);
            mmA[2] = MFMA16(qf[0][0], pe2a, mmA[2]);
            mmA[2] = MFMA16(qf[0][1], pe2b, mmA[2]);
            mmB[1] = MFMA16(qf[1][0], pe2a, mmB[1]);
            mmB[1] = MFMA16(qf[1][1], pe2b, mmB[1]);
            mmB[2] = MFMA16(qf[1][0], pe3a, mmB[2]);
            mmB[2] = MFMA16(qf[1][1], pe3b, mmB[2]);

            // ---- scores + gather + log2-exp + packed P publish ----
#pragma unroll
            for (int sub = 0; sub < 2; ++sub) {
#pragma unroll
                for (int r = 0; r < 4; ++r) {
                    int dl = g * 4 + r;
                    int pl_ = (dl + 15 - lo) & 15;
                    bool cond = pl_ < dl;
                    float v0, v1;
                    if (sub == 0) {
                        v0 = cond ? mmA[2][r] : mmA[1][r];
                        v1 = cond ? mmA[1][r] : mmA[0][r];
                    } else {
                        v0 = cond ? mmB[2][r] : mmB[1][r];
                        v1 = cond ? mmB[1][r] : mmB[0][r];
                    }
                    union { fp16x2 hv; int iv; } pk, gk, pp;
                    pk.hv = __builtin_amdgcn_cvt_pkrtz(v0, v1);
                    int src = (lane & 48) | pl_;
                    gk.iv = __shfl(pk.iv, src, 64);
                    float s0 = sc[sub][0][r] + (float)gk.hv[0];
                    float s1 = sc[sub][1][r] + (float)gk.hv[1];
                    float p0 = __builtin_amdgcn_exp2f(fmaf(s0, gmv[sub][0][r], amL0));
                    float p1 = __builtin_amdgcn_exp2f(fmaf(s1, gmv[sub][1][r], amL1));
                    l_part[sub][r] += p0 + p1;
                    pp.hv = __builtin_amdgcn_cvt_pkrtz(p0, p1);
                    *reinterpret_cast<int*>(Pw + (sub * 16 + dl) * 40 + 2 * lo) = pp.iv;
                }
            }
            // ---- PV (V cols offset by hf*32; Pw same-wave roundtrip) ----
            f16x8 pa0 = *reinterpret_cast<const f16x8*>(Pw + lo * 40 + g * 8);
            f16x8 pa1 = *reinterpret_cast<const f16x8*>(Pw + (16 + lo) * 40 + g * 8);
#pragma unroll
            for (int n = 0; n < 4; ++n) {
                f16x8 vb = *reinterpret_cast<const f16x8*>(
                    Vt + (n * 16 + lo) * 72 + hf * 32 + g * 8);
                o[0][n] = MFMA16(pa0, vb, o[0][n]);
                o[1][n] = MFMA16(pa1, vb, o[1][n]);
            }
        }
        __syncthreads();    // all waves done reading LDS before next ds_write
    }

    // ---- epilogue ----
#pragma unroll
    for (int sub = 0; sub < 2; ++sub)
#pragma unroll
        for (int r = 0; r < 4; ++r) {
            float ls = l_part[sub][r];
            ls += DPPF(ls, 0xB1);
            ls += DPPF(ls, 0x4E);
            ls += DPPF(ls, 0x141);
            ls += DPPF(ls, 0x140);
            float inv = 1.f / ls;
            int l = lw + sub * 16 + g * 4 + r;
#pragma unroll
            for (int n = 0; n < 4; ++n)
                out[((size_t)b * S_ + l) * D_ + h * DH_ + n * 16 + lo] = o[sub][n][r] * inv;
        }
}

// ---------------------------------------------------------------------------
extern "C" void kernel_launch(void* const* d_in, const int* in_sizes, int n_in,
                              void* d_out, int out_size, void* d_ws, size_t ws_size,
                              hipStream_t stream)
{
    const float* hs    = (const float*)d_in[0];
    const float* amask = (const float*)d_in[1];
    const float* gmask = (const float*)d_in[2];
    const float* Wq    = (const float*)d_in[3];
    const float* bq    = (const float*)d_in[4];
    const float* Wk    = (const float*)d_in[5];
    const float* bk    = (const float*)d_in[6];
    const float* Wv    = (const float*)d_in[7];
    const float* bv    = (const float*)d_in[8];
    const float* dist  = (const float*)d_in[9];
    float* out = (float*)d_out;

    const size_t per = (size_t)B_ * H_ * S_ * DH_;   // 4M f16
    f16* qh  = (f16*)d_ws;
    f16* kh  = qh + per;
    f16* vt  = kh + per;
    f16* wht = vt + per;                              // 3M f16
    f16* pe  = wht + (size_t)3 * D_ * D_;             // 4096*64 f16

    split_w_kernel<<<dim3(16, 16, 3), 256, 0, stream>>>(Wq, Wk, Wv, wht);
    pe_convert_kernel<<<dim3(1024), 256, 0, stream>>>(dist, pe);

    dim3 g1((B_ * S_) / 128, D_ / 128, 3);
    mfma_proj_kernel<<<g1, 256, 0, stream>>>(hs, wht, bq, bk, bv,
                                             qh, kh, vt);

    dim3 g2(S_ / 128, B_ * H_);
    attn_mfma_kernel<<<g2, 256, 0, stream>>>(qh, kh, vt, pe,
                                             gmask, amask, out);
}

// Round 21
// 164.101 us; speedup vs baseline: 1.7482x; 1.7482x over previous
//
#include <hip/hip_runtime.h>
#include <math.h>

#define B_ 2
#define S_ 2048
#define D_ 1024
#define H_ 16
#define DH_ 64

typedef _Float16 f16;
typedef _Float16 f16x8 __attribute__((ext_vector_type(8)));
typedef _Float16 f16x4 __attribute__((ext_vector_type(4)));
typedef __fp16 fp16x2 __attribute__((ext_vector_type(2)));
typedef float f32x4 __attribute__((ext_vector_type(4)));

#define MFMA16(a, b, c) __builtin_amdgcn_mfma_f32_16x16x32_f16(a, b, c, 0, 0, 0)
#define LOG2E 1.44269504088896f
#define SHIFT_L2 8.65617024533378f   // 6 * log2(e)

// DPP cross-lane move on VALU pipe (row = 16 lanes on CDNA).
#define DPPF(x, ctrl) \
    __int_as_float(__builtin_amdgcn_mov_dpp(__float_as_int(x), (ctrl), 0xF, 0xF, true))

// k-slot permutation within each 32-column V tile: position p holds
// k = (p>>1) + 16*(p&1)  (pairs (k, k+16) adjacent -> b32 P writes).
__device__ __forceinline__ int permc(int c) {
    return (c & 32) | ((c & 15) << 1) | ((c >> 4) & 1);
}

// ---------------------------------------------------------------------------
// W [k][n] fp32 -> Wht [n][k] f16 (transposed, 3 weights via z).
// ---------------------------------------------------------------------------
__global__ __launch_bounds__(256) void split_w_kernel(
    const float* __restrict__ Wq, const float* __restrict__ Wk,
    const float* __restrict__ Wv, f16* __restrict__ wht)
{
    __shared__ float T[64][69];
    const float* W = (blockIdx.z == 0) ? Wq : (blockIdx.z == 1) ? Wk : Wv;
    f16* ht = wht + (size_t)blockIdx.z * D_ * D_;
    const int t  = threadIdx.x;
    const int k0 = blockIdx.x * 64;
    const int n0 = blockIdx.y * 64;

#pragma unroll
    for (int it = 0; it < 4; ++it) {
        int idx = t + it * 256;
        int row = idx >> 4;
        int c4  = (idx & 15) * 4;
        float4 v = *reinterpret_cast<const float4*>(&W[(size_t)(k0 + row) * D_ + n0 + c4]);
        T[row][c4 + 0] = v.x; T[row][c4 + 1] = v.y;
        T[row][c4 + 2] = v.z; T[row][c4 + 3] = v.w;
    }
    __syncthreads();
#pragma unroll
    for (int it = 0; it < 4; ++it) {
        int idx = t + it * 256;
        int nl = idx >> 4;
        int kc = (idx & 15) * 4;
        f16x4 h4;
#pragma unroll
        for (int j = 0; j < 4; ++j) h4[j] = (f16)T[kc + j][nl];
        *reinterpret_cast<f16x4*>(&ht[(size_t)(n0 + nl) * D_ + k0 + kc]) = h4;
    }
}

// ---------------------------------------------------------------------------
// dist fp32 [4095][64] -> pe f16 [4096][64] (row 4095 dups 4094).
// ---------------------------------------------------------------------------
__global__ __launch_bounds__(256) void pe_convert_kernel(
    const float* __restrict__ dist, f16* __restrict__ pe)
{
    int i = blockIdx.x * 256 + threadIdx.x;
    if (i < 4096 * 16) {
        int src = (i < 4095 * 16) ? i : (i - 16);
        float4 v = reinterpret_cast<const float4*>(dist)[src];
        f16x4 o = {(f16)v.x, (f16)v.y, (f16)v.z, (f16)v.w};
        *reinterpret_cast<f16x4*>(&pe[(size_t)i * 4]) = o;
    }
}

// ---------------------------------------------------------------------------
// MFMA QKV projection, 1-term f16, BK=64.
// Q: PRE-SCALED by 0.125 (folds softmax scale; QK and bias terms both linear
// in q). Q,K: f16 [B,H,S,64] coalesced. V: f16 transposed, k-slot permuted.
// ---------------------------------------------------------------------------
__global__ __launch_bounds__(256) void mfma_proj_kernel(
    const float* __restrict__ A,
    const f16* __restrict__ wht,
    const float* __restrict__ bq, const float* __restrict__ bk,
    const float* __restrict__ bv,
    f16* __restrict__ qh, f16* __restrict__ kh,
    f16* __restrict__ vt)
{
    __shared__ __align__(16) f16 SM[18432];          // 36 KB
    f16* Ah = SM;                                     // [128][72]
    f16* Wh = SM + 9216;                              // [128][72]

    const int z = blockIdx.z;
    const f16* wh_g = wht + (size_t)z * D_ * D_;
    const float* bias = (z == 0) ? bq : (z == 1) ? bk : bv;
    const float oscale = (z == 0) ? 0.125f : 1.0f;

    const int t    = threadIdx.x;
    const int w    = t >> 6;
    const int lane = t & 63;
    const int lo   = lane & 15;
    const int g    = lane >> 4;
    const int wrow = w >> 1;
    const int wcol = w & 1;
    const int m0   = blockIdx.x * 128;
    const int n0   = blockIdx.y * 128;

    f32x4 acc[4][4];
#pragma unroll
    for (int i = 0; i < 4; ++i)
#pragma unroll
        for (int j = 0; j < 4; ++j) acc[i][j] = (f32x4){0.f, 0.f, 0.f, 0.f};

    for (int k0 = 0; k0 < D_; k0 += 64) {
        __syncthreads();
#pragma unroll
        for (int it = 0; it < 8; ++it) {
            int idx = t + it * 256;
            int row = idx >> 4;
            int c   = idx & 15;
            float4 v = *reinterpret_cast<const float4*>(
                &A[(size_t)(m0 + row) * D_ + k0 + c * 4]);
            f16x4 h4 = {(f16)v.x, (f16)v.y, (f16)v.z, (f16)v.w};
            *reinterpret_cast<f16x4*>(&Ah[row * 72 + c * 4]) = h4;
        }
#pragma unroll
        for (int it = 0; it < 4; ++it) {
            int idx = t + it * 256;
            int row = idx >> 3;
            int c   = idx & 7;
            *reinterpret_cast<f16x8*>(&Wh[row * 72 + c * 8]) =
                *reinterpret_cast<const f16x8*>(&wh_g[(size_t)(n0 + row) * D_ + k0 + c * 8]);
        }
        __syncthreads();

#pragma unroll
        for (int ks = 0; ks < 2; ++ks) {
            f16x8 ah[4], whf[4];
#pragma unroll
            for (int m = 0; m < 4; ++m)
                ah[m] = *reinterpret_cast<const f16x8*>(
                    &Ah[(wrow * 64 + m * 16 + lo) * 72 + ks * 32 + g * 8]);
#pragma unroll
            for (int n = 0; n < 4; ++n)
                whf[n] = *reinterpret_cast<const f16x8*>(
                    &Wh[(wcol * 64 + n * 16 + lo) * 72 + ks * 32 + g * 8]);
#pragma unroll
            for (int m = 0; m < 4; ++m)
#pragma unroll
                for (int n = 0; n < 4; ++n)
                    acc[m][n] = MFMA16(ah[m], whf[n], acc[m][n]);
        }
    }

    float bias_v[4];
#pragma unroll
    for (int n = 0; n < 4; ++n) bias_v[n] = bias[n0 + wcol * 64 + n * 16 + lo];

    __syncthreads();
    f16* vtile = SM + w * 4608;           // per-wave [64][72]
    const int bb = m0 >> 11;

    if (z < 2) {
        f16* hd = (z == 0) ? qh : kh;
#pragma unroll
        for (int n = 0; n < 4; ++n)
#pragma unroll
            for (int m = 0; m < 4; ++m)
#pragma unroll
                for (int r = 0; r < 4; ++r)
                    vtile[(m * 16 + g * 4 + r) * 72 + n * 16 + lo] =
                        (f16)((acc[m][n][r] + bias_v[n]) * oscale);
        int s_base = (m0 & (S_ - 1)) + wrow * 64;
        int col0   = n0 + wcol * 64;
        int hh     = col0 >> 6;
        size_t base = ((size_t)(bb * H_ + hh) * S_ + s_base) * DH_;
#pragma unroll
        for (int it = 0; it < 8; ++it) {
            int idx = lane + it * 64;
            int rl  = idx >> 3;
            int ch  = idx & 7;
            f16x8 vv = *reinterpret_cast<const f16x8*>(&vtile[rl * 72 + ch * 8]);
            *reinterpret_cast<f16x8*>(&hd[base + (size_t)rl * DH_ + ch * 8]) = vv;
        }
    } else {
#pragma unroll
        for (int n = 0; n < 4; ++n)
#pragma unroll
            for (int m = 0; m < 4; ++m)
#pragma unroll
                for (int r = 0; r < 4; ++r) {
                    int c = m * 16 + g * 4 + r;
                    vtile[(n * 16 + lo) * 72 + permc(c)] =
                        (f16)(acc[m][n][r] + bias_v[n]);
                }
        int s_base = (m0 & (S_ - 1)) + wrow * 64;
#pragma unroll
        for (int it = 0; it < 8; ++it) {
            int idx = lane + it * 64;
            int cl  = idx >> 3;
            int mc  = idx & 7;
            f16x8 vv = *reinterpret_cast<const f16x8*>(&vtile[cl * 72 + mc * 8]);
            int col = n0 + wcol * 64 + cl;
            int hh  = col >> 6;
            int dh  = col & 63;
            *reinterpret_cast<f16x8*>(
                &vt[((size_t)(bb * H_ + hh) * DH_ + dh) * S_ + s_base + mc * 8]) = vv;
        }
    }
}

// ---------------------------------------------------------------------------
// MFMA flash attention, v14 (R19 optimum): R16 structure + log2-domain
// softmax. Q pre-scaled by 0.125; p = exp2((sc+b)*gmL + amL) with
// gmL = gm*log2e (folded at load), amL = am*log2e - 6*log2e.
// LDS PE ring + register rotation, reg-staged K/V, hoisted gm/am,
// packed P publish, 2 barriers/iter.
// ---------------------------------------------------------------------------
__global__ __launch_bounds__(256) void attn_mfma_kernel(
    const f16* __restrict__ qh, const f16* __restrict__ kh,
    const f16* __restrict__ vt, const f16* __restrict__ pe,
    const float* __restrict__ gm, const float* __restrict__ am,
    float* __restrict__ out)
{
    __shared__ __align__(16) f16 Kh[32 * 72];
    __shared__ __align__(16) f16 Vt[64 * 40];
    __shared__ __align__(16) f16 PE[256 * 72];
    __shared__ __align__(16) f16 Pl[4 * 32 * 40];

    const int t    = threadIdx.x;
    const int w    = t >> 6;
    const int lane = t & 63;
    const int lo   = lane & 15;
    const int g    = lane >> 4;
    const int bh   = blockIdx.y;
    const int b    = bh >> 4;
    const int h    = bh & 15;
    const int l0   = blockIdx.x * 128;
    const int lw   = l0 + w * 32;

    const int krow = t >> 3, kc8 = (t & 7) * 8;
    const int vrow = t >> 2, vc8 = (t & 3) * 8;

    f16x8 qf[2][2];
#pragma unroll
    for (int sub = 0; sub < 2; ++sub) {
        size_t qbase = ((size_t)bh * S_ + lw + sub * 16 + lo) * DH_ + g * 8;
        qf[sub][0] = *reinterpret_cast<const f16x8*>(qh + qbase);
        qf[sub][1] = *reinterpret_cast<const f16x8*>(qh + qbase + 32);
    }

#pragma unroll
    for (int i = 0; i < 4; ++i) {
        int idx = t + i * 256;
        int row = idx >> 3, c8 = (idx & 7) * 8;
        int logical = l0 + 2048 + row;
        int gl = logical > 4095 ? 4095 : logical;
        *reinterpret_cast<f16x8*>(PE + (size_t)(logical & 255) * 72 + c8) =
            *reinterpret_cast<const f16x8*>(pe + (size_t)gl * DH_ + c8);
    }

    f16x8 kreg, vreg, pereg;
    kreg  = *reinterpret_cast<const f16x8*>(kh + ((size_t)bh * S_ + krow) * DH_ + kc8);
    vreg  = *reinterpret_cast<const f16x8*>(vt + ((size_t)bh * DH_ + vrow) * S_ + vc8);
    pereg = *reinterpret_cast<const f16x8*>(pe + (size_t)(l0 + 2016 + krow) * DH_ + kc8);

    f32x4 o[2][4];
#pragma unroll
    for (int sub = 0; sub < 2; ++sub)
#pragma unroll
        for (int n = 0; n < 4; ++n) o[sub][n] = (f32x4){0.f, 0.f, 0.f, 0.f};
    float l_part[2][4] = {{0.f, 0.f, 0.f, 0.f}, {0.f, 0.f, 0.f, 0.f}};

    f16* Pw = Pl + w * 32 * 40;

    f16x8 pe0a, pe0b, pe1a, pe1b, pe2a, pe2b, pe3a, pe3b;

    for (int r0 = 0; r0 < S_; r0 += 32) {
        const int g0 = l0 + 2016 - r0;
        *reinterpret_cast<f16x8*>(Kh + krow * 72 + kc8) = kreg;
        *reinterpret_cast<f16x8*>(Vt + vrow * 40 + vc8) = vreg;
        *reinterpret_cast<f16x8*>(PE + (size_t)((g0 + krow) & 255) * 72 + kc8) = pereg;
        __syncthreads();

        if (r0 + 32 < S_) {
            int r0n = r0 + 32;
            kreg  = *reinterpret_cast<const f16x8*>(
                kh + ((size_t)bh * S_ + r0n + krow) * DH_ + kc8);
            vreg  = *reinterpret_cast<const f16x8*>(
                vt + ((size_t)bh * DH_ + vrow) * S_ + r0n + vc8);
            pereg = *reinterpret_cast<const f16x8*>(
                pe + (size_t)(g0 - 32 + krow) * DH_ + kc8);
        }
        // hoisted gm/am loads, folded into log2 domain
        float gmv[2][2][4];
#pragma unroll
        for (int sub = 0; sub < 2; ++sub)
#pragma unroll
            for (int r = 0; r < 4; ++r) {
                size_t grow = (size_t)(lw + sub * 16 + g * 4 + r) * S_ + r0;
                gmv[sub][0][r] = gm[grow + lo] * LOG2E;
                gmv[sub][1][r] = gm[grow + 16 + lo] * LOG2E;
            }
        float amL0 = fmaf(am[b * S_ + r0 + lo],      LOG2E, -SHIFT_L2);
        float amL1 = fmaf(am[b * S_ + r0 + 16 + lo], LOG2E, -SHIFT_L2);

        {
            int pr0 = (g0 + w * 32 + lo) & 255;
            int pr1 = (g0 + w * 32 + 16 + lo) & 255;
            f16x8 n0a = *reinterpret_cast<const f16x8*>(PE + (size_t)pr0 * 72 + g * 8);
            f16x8 n0b = *reinterpret_cast<const f16x8*>(PE + (size_t)pr0 * 72 + 32 + g * 8);
            f16x8 n1a = *reinterpret_cast<const f16x8*>(PE + (size_t)pr1 * 72 + g * 8);
            f16x8 n1b = *reinterpret_cast<const f16x8*>(PE + (size_t)pr1 * 72 + 32 + g * 8);
            if (r0 == 0) {
                int pr2 = (g0 + w * 32 + 32 + lo) & 255;
                int pr3 = (g0 + w * 32 + 48 + lo) & 255;
                pe2a = *reinterpret_cast<const f16x8*>(PE + (size_t)pr2 * 72 + g * 8);
                pe2b = *reinterpret_cast<const f16x8*>(PE + (size_t)pr2 * 72 + 32 + g * 8);
                pe3a = *reinterpret_cast<const f16x8*>(PE + (size_t)pr3 * 72 + g * 8);
                pe3b = *reinterpret_cast<const f16x8*>(PE + (size_t)pr3 * 72 + 32 + g * 8);
            } else {
                pe2a = pe0a; pe2b = pe0b;
                pe3a = pe1a; pe3b = pe1b;
            }
            pe0a = n0a; pe0b = n0b;
            pe1a = n1a; pe1b = n1b;
        }

        f32x4 sc[2][2];
        sc[0][0] = (f32x4){0.f,0.f,0.f,0.f}; sc[0][1] = (f32x4){0.f,0.f,0.f,0.f};
        sc[1][0] = (f32x4){0.f,0.f,0.f,0.f}; sc[1][1] = (f32x4){0.f,0.f,0.f,0.f};
#pragma unroll
        for (int u = 0; u < 2; ++u)
#pragma unroll
            for (int s = 0; s < 2; ++s) {
                f16x8 kb = *reinterpret_cast<const f16x8*>(
                    Kh + (u * 16 + lo) * 72 + s * 32 + g * 8);
                sc[0][u] = MFMA16(qf[0][s], kb, sc[0][u]);
                sc[1][u] = MFMA16(qf[1][s], kb, sc[1][u]);
            }
        f32x4 mmA[3], mmB[3];
#pragma unroll
        for (int i = 0; i < 3; ++i) {
            mmA[i] = (f32x4){0.f,0.f,0.f,0.f};
            mmB[i] = (f32x4){0.f,0.f,0.f,0.f};
        }
        mmA[0] = MFMA16(qf[0][0], pe0a, mmA[0]);
        mmA[0] = MFMA16(qf[0][1], pe0b, mmA[0]);
        mmA[1] = MFMA16(qf[0][0], pe1a, mmA[1]);
        mmA[1] = MFMA16(qf[0][1], pe1b, mmA[1]);
        mmB[0] = MFMA16(qf[1][0], pe1a, mmB[0]);
        mmB[0] = MFMA16(qf[1][1], pe1b, mmB[0]);
        mmA[2] = MFMA16(qf[0][0], pe2a, mmA[2]);
        mmA[2] = MFMA16(qf[0][1], pe2b, mmA[2]);
        mmB[1] = MFMA16(qf[1][0], pe2a, mmB[1]);
        mmB[1] = MFMA16(qf[1][1], pe2b, mmB[1]);
        mmB[2] = MFMA16(qf[1][0], pe3a, mmB[2]);
        mmB[2] = MFMA16(qf[1][1], pe3b, mmB[2]);

#pragma unroll
        for (int sub = 0; sub < 2; ++sub) {
#pragma unroll
            for (int r = 0; r < 4; ++r) {
                int dl = g * 4 + r;
                int pl_ = (dl + 15 - lo) & 15;
                bool cond = pl_ < dl;
                float v0, v1;
                if (sub == 0) {
                    v0 = cond ? mmA[2][r] : mmA[1][r];
                    v1 = cond ? mmA[1][r] : mmA[0][r];
                } else {
                    v0 = cond ? mmB[2][r] : mmB[1][r];
                    v1 = cond ? mmB[1][r] : mmB[0][r];
                }
                union { fp16x2 hv; int iv; } pk, gk, pp;
                pk.hv = __builtin_amdgcn_cvt_pkrtz(v0, v1);
                int src = (lane & 48) | pl_;
                gk.iv = __shfl(pk.iv, src, 64);
                float s0 = sc[sub][0][r] + (float)gk.hv[0];
                float s1 = sc[sub][1][r] + (float)gk.hv[1];
                float p0 = __builtin_amdgcn_exp2f(fmaf(s0, gmv[sub][0][r], amL0));
                float p1 = __builtin_amdgcn_exp2f(fmaf(s1, gmv[sub][1][r], amL1));
                l_part[sub][r] += p0 + p1;
                pp.hv = __builtin_amdgcn_cvt_pkrtz(p0, p1);
                *reinterpret_cast<int*>(Pw + (sub * 16 + dl) * 40 + 2 * lo) = pp.iv;
            }
        }
        f16x8 pa0 = *reinterpret_cast<const f16x8*>(Pw + lo * 40 + g * 8);
        f16x8 pa1 = *reinterpret_cast<const f16x8*>(Pw + (16 + lo) * 40 + g * 8);
#pragma unroll
        for (int n = 0; n < 4; ++n) {
            f16x8 vb = *reinterpret_cast<const f16x8*>(Vt + (n * 16 + lo) * 40 + g * 8);
            o[0][n] = MFMA16(pa0, vb, o[0][n]);
            o[1][n] = MFMA16(pa1, vb, o[1][n]);
        }
        __syncthreads();
    }

#pragma unroll
    for (int sub = 0; sub < 2; ++sub)
#pragma unroll
        for (int r = 0; r < 4; ++r) {
            float ls = l_part[sub][r];
            ls += DPPF(ls, 0xB1);
            ls += DPPF(ls, 0x4E);
            ls += DPPF(ls, 0x141);
            ls += DPPF(ls, 0x140);
            float inv = 1.f / ls;
            int l = lw + sub * 16 + g * 4 + r;
#pragma unroll
            for (int n = 0; n < 4; ++n)
                out[((size_t)b * S_ + l) * D_ + h * DH_ + n * 16 + lo] = o[sub][n][r] * inv;
        }
}

// ---------------------------------------------------------------------------
extern "C" void kernel_launch(void* const* d_in, const int* in_sizes, int n_in,
                              void* d_out, int out_size, void* d_ws, size_t ws_size,
                              hipStream_t stream)
{
    const float* hs    = (const float*)d_in[0];
    const float* amask = (const float*)d_in[1];
    const float* gmask = (const float*)d_in[2];
    const float* Wq    = (const float*)d_in[3];
    const float* bq    = (const float*)d_in[4];
    const float* Wk    = (const float*)d_in[5];
    const float* bk    = (const float*)d_in[6];
    const float* Wv    = (const float*)d_in[7];
    const float* bv    = (const float*)d_in[8];
    const float* dist  = (const float*)d_in[9];
    float* out = (float*)d_out;

    const size_t per = (size_t)B_ * H_ * S_ * DH_;   // 4M f16
    f16* qh  = (f16*)d_ws;
    f16* kh  = qh + per;
    f16* vt  = kh + per;
    f16* wht = vt + per;                              // 3M f16
    f16* pe  = wht + (size_t)3 * D_ * D_;             // 4096*64 f16

    split_w_kernel<<<dim3(16, 16, 3), 256, 0, stream>>>(Wq, Wk, Wv, wht);
    pe_convert_kernel<<<dim3(1024), 256, 0, stream>>>(dist, pe);

    dim3 g1((B_ * S_) / 128, D_ / 128, 3);
    mfma_proj_kernel<<<g1, 256, 0, stream>>>(hs, wht, bq, bk, bv,
                                             qh, kh, vt);

    dim3 g2(S_ / 128, B_ * H_);
    attn_mfma_kernel<<<g2, 256, 0, stream>>>(qh, kh, vt, pe,
                                             gmask, amask, out);
}